// Round 3
// baseline (422.317 us; speedup 1.0000x reference)
//
#include <hip/hip_runtime.h>
#include <hip/hip_bf16.h>
#include <stdint.h>

#define T_TOK 4096
#define DIM   1024
#define HID   2048
#define NE    8

typedef unsigned short ushort_t;
typedef __attribute__((ext_vector_type(8))) short bf16x8;
typedef __attribute__((ext_vector_type(8))) short short8_t;
typedef __attribute__((ext_vector_type(4))) float f32x4;

__device__ __forceinline__ unsigned short f2bf(float f) {
  unsigned u = __float_as_uint(f);
  unsigned r = (u + 0x7fffu + ((u >> 16) & 1u)) >> 16;
  return (unsigned short)r;
}

__device__ __forceinline__ void gl2lds16(const ushort_t* g, ushort_t* l) {
  void* gv = (void*)g;
  __builtin_amdgcn_global_load_lds((__attribute__((address_space(1))) void*)gv,
                                   (__attribute__((address_space(3))) void*)l,
                                   16, 0, 0);
}

__device__ __forceinline__ void decode_tile(int id,
    const float* __restrict__ W1, const float* __restrict__ W2,
    const float* __restrict__ W3,
    ushort_t* __restrict__ w1t, ushort_t* __restrict__ w3t,
    ushort_t* __restrict__ w2t,
    const float*& s, ushort_t*& d, int& R, int& C, int& c0, int& r0) {
  const int which = id >> 12;
  const int sub = id & 4095;
  const int e = sub >> 9, rem = sub & 511;
  const float* src; ushort_t* dst; int cx, ry;
  if (which == 0)      { src = W1; dst = w1t; R = DIM; C = HID; cx = rem & 31; ry = rem >> 5; }
  else if (which == 1) { src = W3; dst = w3t; R = DIM; C = HID; cx = rem & 31; ry = rem >> 5; }
  else                 { src = W2; dst = w2t; R = HID; C = DIM; cx = rem & 15; ry = rem >> 4; }
  s = src + (size_t)e * R * C;
  d = dst + (size_t)e * R * C;
  c0 = cx * 64; r0 = ry * 64;
}

// ================= fused prep (pipelined) =================
// blocks [0,3072): 4 transpose+convert tiles each, double-buffered LDS
// blocks [3072,3328): router compute + x fp32->bf16 (16 tokens/block)
__global__ __launch_bounds__(256)
void prep_kernel(const float* __restrict__ x, const float* __restrict__ Wr,
                 const float* __restrict__ W1, const float* __restrict__ W2,
                 const float* __restrict__ W3,
                 ushort_t* __restrict__ xb,
                 ushort_t* __restrict__ w1t, ushort_t* __restrict__ w3t,
                 ushort_t* __restrict__ w2t,
                 int* __restrict__ eidx, float2* __restrict__ gpair) {
  const int b = blockIdx.x;
  const int tid = threadIdx.x;
  __shared__ float lds[2][64][65];

  if (b < 3072) {
    const float* s; ushort_t* d; int R, C, c0, r0;
    decode_tile(b * 4, W1, W2, W3, w1t, w3t, w2t, s, d, R, C, c0, r0);
    float4 v[4];
#pragma unroll
    for (int p = 0; p < 4; p++) {
      int idx = p * 256 + tid; int r = idx >> 4, c4 = idx & 15;
      v[p] = *(const float4*)(s + (size_t)(r0 + r) * C + c0 + c4 * 4);
    }
#pragma unroll
    for (int i = 0; i < 4; i++) {
      // write current tile regs -> lds[i&1]
#pragma unroll
      for (int p = 0; p < 4; p++) {
        int idx = p * 256 + tid; int r = idx >> 4, c4 = idx & 15;
        float* row = &lds[i & 1][r][c4 * 4];
        row[0] = v[p].x; row[1] = v[p].y; row[2] = v[p].z; row[3] = v[p].w;
      }
      // save dst params of current tile
      ushort_t* dS = d; const int RS = R, c0S = c0, r0S = r0;
      // issue loads for next tile (overlap with store phase)
      if (i < 3) {
        decode_tile(b * 4 + i + 1, W1, W2, W3, w1t, w3t, w2t, s, d, R, C, c0, r0);
#pragma unroll
        for (int p = 0; p < 4; p++) {
          int idx = p * 256 + tid; int r = idx >> 4, c4 = idx & 15;
          v[p] = *(const float4*)(s + (size_t)(r0 + r) * C + c0 + c4 * 4);
        }
      }
      __syncthreads();
      // convert + store current tile from lds[i&1]
#pragma unroll
      for (int p = 0; p < 2; p++) {
        int idx = p * 256 + tid; int cc = idx >> 3, r8 = idx & 7;
        short8_t o;
#pragma unroll
        for (int k = 0; k < 8; k++) o[k] = (short)f2bf(lds[i & 1][r8 * 8 + k][cc]);
        *(short8_t*)(dS + (size_t)(c0S + cc) * RS + r0S + r8 * 8) = o;
      }
    }
  } else {
    // ---- router compute + x convert: 4 tokens per wave ----
    const int wave = tid >> 6;
    const int lane = tid & 63;
#pragma unroll
    for (int j = 0; j < 4; j++) {
      const int t = (b - 3072) * 16 + wave * 4 + j;
      const float* xr = x + (size_t)t * DIM;
      ushort_t* xbr = xb + (size_t)t * DIM;
      float acc[NE];
#pragma unroll
      for (int e = 0; e < NE; e++) acc[e] = 0.f;
#pragma unroll
      for (int it = 0; it < 4; it++) {
        int d4 = it * 64 + lane;                 // float4 index within the row
        float4 v = ((const float4*)xr)[d4];
        ushort4 o;
        o.x = f2bf(v.x); o.y = f2bf(v.y); o.z = f2bf(v.z); o.w = f2bf(v.w);
        ((ushort4*)xbr)[d4] = o;
        const float* wr = Wr + (size_t)d4 * 4 * NE;
        float c[4] = {v.x, v.y, v.z, v.w};
#pragma unroll
        for (int cc = 0; cc < 4; cc++)
#pragma unroll
          for (int e = 0; e < NE; e++) acc[e] += c[cc] * wr[cc * NE + e];
      }
#pragma unroll
      for (int off = 32; off >= 1; off >>= 1) {
#pragma unroll
        for (int e = 0; e < NE; e++) acc[e] += __shfl_xor(acc[e], off, 64);
      }
      if (lane == 0) {
        int i1 = 0;
#pragma unroll
        for (int e = 1; e < NE; e++) if (acc[e] > acc[i1]) i1 = e;
        int i2 = (i1 == 0) ? 1 : 0;
#pragma unroll
        for (int e = 0; e < NE; e++) {
          if (e == i1) continue;
          if (acc[e] > acc[i2]) i2 = e;
        }
        float r = expf(acc[i2] - acc[i1]);       // p2/p1
        float g1 = 1.f / (1.f + r);
        eidx[t] = i1 | (i2 << 8);
        gpair[t] = make_float2(g1, 1.f - g1);
      }
    }
  }
}

// ================= compaction: LDS atomics, one block =================
__global__ __launch_bounds__(1024)
void compact_kernel(const int* __restrict__ eidx, const float2* __restrict__ gpair,
                    int* __restrict__ cnt, int* __restrict__ tok,
                    float* __restrict__ gate, int* __restrict__ ppos) {
  __shared__ int lcnt[NE];
  const int tid = threadIdx.x;
  if (tid < NE) lcnt[tid] = 0;
  __syncthreads();
  for (int t = tid; t < T_TOK; t += 1024) {
    int pk = eidx[t];
    int i1 = pk & 0xff, i2 = (pk >> 8) & 0xff;
    float2 g = gpair[t];
    int p1 = atomicAdd(&lcnt[i1], 1);
    tok[i1 * T_TOK + p1] = t; gate[i1 * T_TOK + p1] = g.x;
    int p2 = atomicAdd(&lcnt[i2], 1);
    tok[i2 * T_TOK + p2] = t; gate[i2 * T_TOK + p2] = g.y;
    ppos[t] = p1 | (p2 << 16);
  }
  __syncthreads();
  if (tid < NE) cnt[tid] = lcnt[tid];
}

// ================= GEMM1: h = gate*silu(x@W1)*(x@W3), BK=64 =================
// 128m x 64h tile; per wave 64x32 for BOTH W1,W3; 32 MFMA per barrier
__global__ __launch_bounds__(256, 3)
void gemm1_kernel(const ushort_t* __restrict__ xb,
                  const ushort_t* __restrict__ w1t,
                  const ushort_t* __restrict__ w3t,
                  const int* __restrict__ tok,
                  const float* __restrict__ gates,
                  const int* __restrict__ cnt,
                  ushort_t* __restrict__ hbuf) {
  const int e = blockIdx.z, mt = blockIdx.y, nt = blockIdx.x;
  const int Ne = cnt[e];
  if (mt * 128 >= Ne) return;
  int be = 0;
#pragma unroll
  for (int i = 0; i < NE; i++) be += (i < e) ? cnt[i] : 0;

  __shared__ __attribute__((aligned(16))) ushort_t lA[128 * 64];
  __shared__ __attribute__((aligned(16))) ushort_t lB1[64 * 64];
  __shared__ __attribute__((aligned(16))) ushort_t lB3[64 * 64];

  const int tid = threadIdx.x, lane = tid & 63, wave = tid >> 6;
  const int kco = ((tid & 7) ^ ((tid >> 3) & 7)) * 8;

  const ushort_t* pA[4];
#pragma unroll
  for (int it = 0; it < 4; it++) {
    int rowg = mt * 128 + it * 32 + (tid >> 3);
    int t = (rowg < Ne) ? tok[e * T_TOK + rowg] : 0;
    pA[it] = xb + (size_t)t * DIM + kco;
  }
  const int h0 = nt * 64;
  const ushort_t* pB1[2];
  const ushort_t* pB3[2];
#pragma unroll
  for (int it = 0; it < 2; it++) {
    int row = h0 + it * 32 + (tid >> 3);
    pB1[it] = w1t + ((size_t)e * HID + row) * DIM + kco;
    pB3[it] = w3t + ((size_t)e * HID + row) * DIM + kco;
  }

  f32x4 c1[4][2], c3[4][2];
#pragma unroll
  for (int i = 0; i < 4; i++)
#pragma unroll
    for (int j = 0; j < 2; j++) {
      c1[i][j] = (f32x4){0.f, 0.f, 0.f, 0.f};
      c3[i][j] = (f32x4){0.f, 0.f, 0.f, 0.f};
    }

  const int wm = (wave >> 1) * 64, wn = (wave & 1) * 32;
  const int m = lane & 15, kq = lane >> 4;
  int aRow[4], bRow[2], cSlot[2];
#pragma unroll
  for (int i = 0; i < 4; i++) aRow[i] = (wm + i * 16 + m) * 64;
#pragma unroll
  for (int j = 0; j < 2; j++) bRow[j] = (wn + j * 16 + m) * 64;
#pragma unroll
  for (int u = 0; u < 2; u++) cSlot[u] = ((u * 4 + kq) ^ (m & 7)) * 8;

  for (int k0 = 0; k0 < DIM; k0 += 64) {
#pragma unroll
    for (int it = 0; it < 4; it++) gl2lds16(pA[it] + k0, lA + (it * 256 + tid) * 8);
#pragma unroll
    for (int it = 0; it < 2; it++) {
      gl2lds16(pB1[it] + k0, lB1 + (it * 256 + tid) * 8);
      gl2lds16(pB3[it] + k0, lB3 + (it * 256 + tid) * 8);
    }
    __syncthreads();
#pragma unroll
    for (int u = 0; u < 2; u++) {
      bf16x8 a[4], b1f[2], b3f[2];
#pragma unroll
      for (int i = 0; i < 4; i++) a[i] = *(const bf16x8*)(lA + aRow[i] + cSlot[u]);
#pragma unroll
      for (int j = 0; j < 2; j++) {
        b1f[j] = *(const bf16x8*)(lB1 + bRow[j] + cSlot[u]);
        b3f[j] = *(const bf16x8*)(lB3 + bRow[j] + cSlot[u]);
      }
#pragma unroll
      for (int i = 0; i < 4; i++)
#pragma unroll
        for (int j = 0; j < 2; j++) {
          c1[i][j] = __builtin_amdgcn_mfma_f32_16x16x32_bf16(a[i], b1f[j], c1[i][j], 0, 0, 0);
          c3[i][j] = __builtin_amdgcn_mfma_f32_16x16x32_bf16(a[i], b3f[j], c3[i][j], 0, 0, 0);
        }
    }
    __syncthreads();
  }

  const int m4 = lane >> 4;
#pragma unroll
  for (int i = 0; i < 4; i++) {
#pragma unroll
    for (int j = 0; j < 2; j++) {
      int hcol = h0 + wn + j * 16 + m;
#pragma unroll
      for (int reg = 0; reg < 4; reg++) {
        int rowg = mt * 128 + wm + i * 16 + m4 * 4 + reg;
        if (rowg < Ne) {
          float v1 = c1[i][j][reg];
          float v3 = c3[i][j][reg];
          float g = gates[e * T_TOK + rowg];
          float hv = g * (v1 / (1.f + expf(-v1))) * v3;
          hbuf[(size_t)(be + rowg) * HID + hcol] = f2bf(hv);
        }
      }
    }
  }
}

// ================= GEMM2: out2[slot] = h @ W2, BK=64 (plain stores) =================
// 128m x 128d tile; per wave 64x64; 32 MFMA per barrier
__global__ __launch_bounds__(256, 3)
void gemm2_kernel(const ushort_t* __restrict__ hbuf,
                  const ushort_t* __restrict__ w2t,
                  const int* __restrict__ tok,
                  const int* __restrict__ cnt,
                  float* __restrict__ out2) {
  const int e = blockIdx.z, mt = blockIdx.y, nt = blockIdx.x;
  const int Ne = cnt[e];
  if (mt * 128 >= Ne) return;
  int be = 0;
#pragma unroll
  for (int i = 0; i < NE; i++) be += (i < e) ? cnt[i] : 0;

  __shared__ __attribute__((aligned(16))) ushort_t lA[128 * 64];
  __shared__ __attribute__((aligned(16))) ushort_t lB[128 * 64];

  const int tid = threadIdx.x, lane = tid & 63, wave = tid >> 6;
  const int kco = ((tid & 7) ^ ((tid >> 3) & 7)) * 8;

  const ushort_t* pA[4];
#pragma unroll
  for (int it = 0; it < 4; it++) {
    int rr = min(mt * 128 + it * 32 + (tid >> 3), Ne - 1);
    pA[it] = hbuf + (size_t)(be + rr) * HID + kco;
  }
  const int d0 = nt * 128;
  const ushort_t* pB[4];
#pragma unroll
  for (int it = 0; it < 4; it++) {
    int row = d0 + it * 32 + (tid >> 3);
    pB[it] = w2t + ((size_t)e * DIM + row) * HID + kco;
  }

  f32x4 c[4][4];
#pragma unroll
  for (int i = 0; i < 4; i++)
#pragma unroll
    for (int j = 0; j < 4; j++) c[i][j] = (f32x4){0.f, 0.f, 0.f, 0.f};

  const int wm = (wave >> 1) * 64, wn = (wave & 1) * 64;
  const int m = lane & 15, kq = lane >> 4;
  int aRow[4], bRow[4], cSlot[2];
#pragma unroll
  for (int i = 0; i < 4; i++) aRow[i] = (wm + i * 16 + m) * 64;
#pragma unroll
  for (int j = 0; j < 4; j++) bRow[j] = (wn + j * 16 + m) * 64;
#pragma unroll
  for (int u = 0; u < 2; u++) cSlot[u] = ((u * 4 + kq) ^ (m & 7)) * 8;

  for (int k0 = 0; k0 < HID; k0 += 64) {
#pragma unroll
    for (int it = 0; it < 4; it++) {
      gl2lds16(pA[it] + k0, lA + (it * 256 + tid) * 8);
      gl2lds16(pB[it] + k0, lB + (it * 256 + tid) * 8);
    }
    __syncthreads();
#pragma unroll
    for (int u = 0; u < 2; u++) {
      bf16x8 a[4], bf[4];
#pragma unroll
      for (int i = 0; i < 4; i++) a[i] = *(const bf16x8*)(lA + aRow[i] + cSlot[u]);
#pragma unroll
      for (int j = 0; j < 4; j++) bf[j] = *(const bf16x8*)(lB + bRow[j] + cSlot[u]);
#pragma unroll
      for (int i = 0; i < 4; i++)
#pragma unroll
        for (int j = 0; j < 4; j++)
          c[i][j] = __builtin_amdgcn_mfma_f32_16x16x32_bf16(a[i], bf[j], c[i][j], 0, 0, 0);
    }
    __syncthreads();
  }

  const int m4 = lane >> 4;
#pragma unroll
  for (int i = 0; i < 4; i++) {
    int rowg = mt * 128 + wm + i * 16 + m4 * 4;
    if (rowg >= Ne) continue;
#pragma unroll
    for (int reg = 0; reg < 4; reg++) {
      int rg = rowg + reg;
      if (rg < Ne) {
        float* orow = out2 + (size_t)(be + rg) * DIM;
#pragma unroll
        for (int j = 0; j < 4; j++) {
          int dcol = d0 + wn + j * 16 + m;
          orow[dcol] = c[i][j][reg];
        }
      }
    }
  }
}

// ================= combine: out[t] = out2[slot1(t)] + out2[slot2(t)] =================
// 512 blocks x 8 tokens
__global__ __launch_bounds__(256)
void combine_kernel(const float* __restrict__ out2, const int* __restrict__ eidx,
                    const int* __restrict__ ppos, const int* __restrict__ cnt,
                    float* __restrict__ out) {
  const int tid = threadIdx.x;
  int c[NE];
#pragma unroll
  for (int e = 0; e < NE; e++) c[e] = cnt[e];
#pragma unroll
  for (int j = 0; j < 8; j++) {
    const int t = blockIdx.x * 8 + j;
    int pk = eidx[t];
    int i1 = pk & 0xff, i2 = (pk >> 8) & 0xff;
    int pp = ppos[t];
    int p1 = pp & 0xffff, p2 = (pp >> 16) & 0xffff;
    int base1 = 0, base2 = 0;
#pragma unroll
    for (int e = 0; e < NE; e++) {
      base1 += (e < i1) ? c[e] : 0;
      base2 += (e < i2) ? c[e] : 0;
    }
    const float4* r1 = (const float4*)(out2 + (size_t)(base1 + p1) * DIM);
    const float4* r2 = (const float4*)(out2 + (size_t)(base2 + p2) * DIM);
    float4* o = (float4*)(out + (size_t)t * DIM);
    float4 a = r1[tid], b = r2[tid];
    o[tid] = make_float4(a.x + b.x, a.y + b.y, a.z + b.z, a.w + b.w);
  }
}

extern "C" void kernel_launch(void* const* d_in, const int* in_sizes, int n_in,
                              void* d_out, int out_size, void* d_ws, size_t ws_size,
                              hipStream_t stream) {
  (void)in_sizes; (void)n_in; (void)ws_size; (void)out_size;
  const float* x  = (const float*)d_in[0];
  const float* Wr = (const float*)d_in[1];
  const float* W1 = (const float*)d_in[2];
  const float* W2 = (const float*)d_in[3];
  const float* W3 = (const float*)d_in[4];
  float* out = (float*)d_out;

  char* w = (char*)d_ws;
  ushort_t* xb   = (ushort_t*)w; w += (size_t)T_TOK * DIM * 2;
  ushort_t* w1t  = (ushort_t*)w; w += (size_t)NE * DIM * HID * 2;
  ushort_t* w3t  = (ushort_t*)w; w += (size_t)NE * DIM * HID * 2;
  ushort_t* w2t  = (ushort_t*)w; w += (size_t)NE * HID * DIM * 2;
  ushort_t* hbuf = (ushort_t*)w; w += (size_t)2 * T_TOK * HID * 2;
  int*    tok   = (int*)w;    w += (size_t)NE * T_TOK * 4;
  float*  gates = (float*)w;  w += (size_t)NE * T_TOK * 4;
  int*    eidx  = (int*)w;    w += (size_t)T_TOK * 4;
  float2* gpair = (float2*)w; w += (size_t)T_TOK * 8;
  int*    cnt   = (int*)w;    w += 128;
  int*    ppos  = (int*)w;    w += (size_t)T_TOK * 4;
  // out2 aliases w1t: w1t is dead after gemm1, out2 written by gemm2 (stream-ordered)
  float*  out2  = (float*)w1t;

  prep_kernel<<<3328, 256, 0, stream>>>(x, Wr, W1, W2, W3, xb, w1t, w3t, w2t,
                                        eidx, gpair);
  compact_kernel<<<1, 1024, 0, stream>>>(eidx, gpair, cnt, tok, gates, ppos);
  gemm1_kernel<<<dim3(HID / 64, 32, NE), 256, 0, stream>>>(xb, w1t, w3t, tok, gates, cnt, hbuf);
  gemm2_kernel<<<dim3(DIM / 128, 32, NE), 256, 0, stream>>>(hbuf, w2t, tok, cnt, out2);
  combine_kernel<<<512, 256, 0, stream>>>(out2, eidx, ppos, cnt, out);
}

// Round 4
// 408.692 us; speedup vs baseline: 1.0333x; 1.0333x over previous
//
#include <hip/hip_runtime.h>
#include <hip/hip_bf16.h>
#include <stdint.h>

#define T_TOK 4096
#define DIM   1024
#define HID   2048
#define NE    8

typedef unsigned short ushort_t;
typedef __attribute__((ext_vector_type(8))) short bf16x8;
typedef __attribute__((ext_vector_type(8))) short short8_t;
typedef __attribute__((ext_vector_type(4))) float f32x4;

__device__ __forceinline__ unsigned short f2bf(float f) {
  unsigned u = __float_as_uint(f);
  unsigned r = (u + 0x7fffu + ((u >> 16) & 1u)) >> 16;
  return (unsigned short)r;
}

__device__ __forceinline__ void gl2lds16(const ushort_t* g, ushort_t* l) {
  void* gv = (void*)g;
  __builtin_amdgcn_global_load_lds((__attribute__((address_space(1))) void*)gv,
                                   (__attribute__((address_space(3))) void*)l,
                                   16, 0, 0);
}

// ================= fused prep =================
// blocks [0,12288): transpose+convert W1/W3/W2 -> bf16 k-contiguous
// blocks [12288,13312): router compute (no atomics) + x fp32->bf16 (4 tokens/block)
__global__ __launch_bounds__(256)
void prep_kernel(const float* __restrict__ x, const float* __restrict__ Wr,
                 const float* __restrict__ W1, const float* __restrict__ W2,
                 const float* __restrict__ W3,
                 ushort_t* __restrict__ xb,
                 ushort_t* __restrict__ w1t, ushort_t* __restrict__ w3t,
                 ushort_t* __restrict__ w2t,
                 int* __restrict__ eidx, float2* __restrict__ gpair) {
  const int b = blockIdx.x;
  const int tid = threadIdx.x;
  __shared__ float lds[64][65];

  if (b < 12288) {
    // ---- transpose+convert: src fp32 [R][C] -> dst bf16 [C][R] ----
    const float* src; ushort_t* dst; int R, C, cx, ry;
    const int which = b >> 12;
    const int id = b & 4095;
    const int e = id >> 9, rem = id & 511;
    if (which == 0)      { src = W1; dst = w1t; R = DIM; C = HID; cx = rem & 31; ry = rem >> 5; }
    else if (which == 1) { src = W3; dst = w3t; R = DIM; C = HID; cx = rem & 31; ry = rem >> 5; }
    else                 { src = W2; dst = w2t; R = HID; C = DIM; cx = rem & 15; ry = rem >> 4; }
    const float* s = src + (size_t)e * R * C;
    ushort_t* d = dst + (size_t)e * R * C;
    const int c0 = cx * 64, r0 = ry * 64;
#pragma unroll
    for (int p = 0; p < 4; p++) {
      int idx = p * 256 + tid;
      int r = idx >> 4, c4 = idx & 15;
      float4 v = *(const float4*)(s + (size_t)(r0 + r) * C + c0 + c4 * 4);
      lds[r][c4 * 4 + 0] = v.x; lds[r][c4 * 4 + 1] = v.y;
      lds[r][c4 * 4 + 2] = v.z; lds[r][c4 * 4 + 3] = v.w;
    }
    __syncthreads();
    // 16B stores: thread -> column cc, 8-row group r8
#pragma unroll
    for (int p = 0; p < 2; p++) {
      int idx = p * 256 + tid;
      int cc = idx >> 3, r8 = idx & 7;
      short8_t o;
#pragma unroll
      for (int k = 0; k < 8; k++) o[k] = (short)f2bf(lds[r8 * 8 + k][cc]);
      *(short8_t*)(d + (size_t)(c0 + cc) * R + r0 + r8 * 8) = o;
    }
  } else {
    // ---- router compute + x convert: one token per wave ----
    const int wave = tid >> 6;
    const int lane = tid & 63;
    const int t = (b - 12288) * 4 + wave;
    const float* xr = x + (size_t)t * DIM;
    ushort_t* xbr = xb + (size_t)t * DIM;
    float acc[NE];
#pragma unroll
    for (int e = 0; e < NE; e++) acc[e] = 0.f;
#pragma unroll
    for (int it = 0; it < 4; it++) {
      int d4 = it * 64 + lane;                 // float4 index within the row
      float4 v = ((const float4*)xr)[d4];
      ushort4 o;
      o.x = f2bf(v.x); o.y = f2bf(v.y); o.z = f2bf(v.z); o.w = f2bf(v.w);
      ((ushort4*)xbr)[d4] = o;
      const float* wr = Wr + (size_t)d4 * 4 * NE;
      float c[4] = {v.x, v.y, v.z, v.w};
#pragma unroll
      for (int cc = 0; cc < 4; cc++)
#pragma unroll
        for (int e = 0; e < NE; e++) acc[e] += c[cc] * wr[cc * NE + e];
    }
#pragma unroll
    for (int off = 32; off >= 1; off >>= 1) {
#pragma unroll
      for (int e = 0; e < NE; e++) acc[e] += __shfl_xor(acc[e], off, 64);
    }
    if (lane == 0) {
      int i1 = 0;
#pragma unroll
      for (int e = 1; e < NE; e++) if (acc[e] > acc[i1]) i1 = e;
      int i2 = (i1 == 0) ? 1 : 0;
#pragma unroll
      for (int e = 0; e < NE; e++) {
        if (e == i1) continue;
        if (acc[e] > acc[i2]) i2 = e;
      }
      float r = expf(acc[i2] - acc[i1]);       // p2/p1
      float g1 = 1.f / (1.f + r);
      eidx[t] = i1 | (i2 << 8);
      gpair[t] = make_float2(g1, 1.f - g1);
    }
  }
}

// ================= compaction: LDS atomics, one block =================
__global__ __launch_bounds__(1024)
void compact_kernel(const int* __restrict__ eidx, const float2* __restrict__ gpair,
                    int* __restrict__ cnt, int* __restrict__ tok,
                    float* __restrict__ gate, int* __restrict__ ppos) {
  __shared__ int lcnt[NE];
  const int tid = threadIdx.x;
  if (tid < NE) lcnt[tid] = 0;
  __syncthreads();
  for (int t = tid; t < T_TOK; t += 1024) {
    int pk = eidx[t];
    int i1 = pk & 0xff, i2 = (pk >> 8) & 0xff;
    float2 g = gpair[t];
    int p1 = atomicAdd(&lcnt[i1], 1);
    tok[i1 * T_TOK + p1] = t; gate[i1 * T_TOK + p1] = g.x;
    int p2 = atomicAdd(&lcnt[i2], 1);
    tok[i2 * T_TOK + p2] = t; gate[i2 * T_TOK + p2] = g.y;
    ppos[t] = p1 | (p2 << 16);
  }
  __syncthreads();
  if (tid < NE) cnt[tid] = lcnt[tid];
}

// ================= GEMM1: h = gate*silu(x@W1)*(x@W3), BK=64 =================
// 128m x 64h tile; per wave 64x32 for BOTH W1,W3; 32 MFMA per barrier
__global__ __launch_bounds__(256, 3)
void gemm1_kernel(const ushort_t* __restrict__ xb,
                  const ushort_t* __restrict__ w1t,
                  const ushort_t* __restrict__ w3t,
                  const int* __restrict__ tok,
                  const float* __restrict__ gates,
                  const int* __restrict__ cnt,
                  ushort_t* __restrict__ hbuf) {
  const int e = blockIdx.z, mt = blockIdx.y, nt = blockIdx.x;
  const int Ne = cnt[e];
  if (mt * 128 >= Ne) return;
  int be = 0;
#pragma unroll
  for (int i = 0; i < NE; i++) be += (i < e) ? cnt[i] : 0;

  __shared__ __attribute__((aligned(16))) ushort_t lA[128 * 64];
  __shared__ __attribute__((aligned(16))) ushort_t lB1[64 * 64];
  __shared__ __attribute__((aligned(16))) ushort_t lB3[64 * 64];

  const int tid = threadIdx.x, lane = tid & 63, wave = tid >> 6;
  const int kco = ((tid & 7) ^ ((tid >> 3) & 7)) * 8;

  const ushort_t* pA[4];
#pragma unroll
  for (int it = 0; it < 4; it++) {
    int rowg = mt * 128 + it * 32 + (tid >> 3);
    int t = (rowg < Ne) ? tok[e * T_TOK + rowg] : 0;
    pA[it] = xb + (size_t)t * DIM + kco;
  }
  const int h0 = nt * 64;
  const ushort_t* pB1[2];
  const ushort_t* pB3[2];
#pragma unroll
  for (int it = 0; it < 2; it++) {
    int row = h0 + it * 32 + (tid >> 3);
    pB1[it] = w1t + ((size_t)e * HID + row) * DIM + kco;
    pB3[it] = w3t + ((size_t)e * HID + row) * DIM + kco;
  }

  f32x4 c1[4][2], c3[4][2];
#pragma unroll
  for (int i = 0; i < 4; i++)
#pragma unroll
    for (int j = 0; j < 2; j++) {
      c1[i][j] = (f32x4){0.f, 0.f, 0.f, 0.f};
      c3[i][j] = (f32x4){0.f, 0.f, 0.f, 0.f};
    }

  const int wm = (wave >> 1) * 64, wn = (wave & 1) * 32;
  const int m = lane & 15, kq = lane >> 4;
  int aRow[4], bRow[2], cSlot[2];
#pragma unroll
  for (int i = 0; i < 4; i++) aRow[i] = (wm + i * 16 + m) * 64;
#pragma unroll
  for (int j = 0; j < 2; j++) bRow[j] = (wn + j * 16 + m) * 64;
#pragma unroll
  for (int u = 0; u < 2; u++) cSlot[u] = ((u * 4 + kq) ^ (m & 7)) * 8;

  for (int k0 = 0; k0 < DIM; k0 += 64) {
#pragma unroll
    for (int it = 0; it < 4; it++) gl2lds16(pA[it] + k0, lA + (it * 256 + tid) * 8);
#pragma unroll
    for (int it = 0; it < 2; it++) {
      gl2lds16(pB1[it] + k0, lB1 + (it * 256 + tid) * 8);
      gl2lds16(pB3[it] + k0, lB3 + (it * 256 + tid) * 8);
    }
    __syncthreads();
#pragma unroll
    for (int u = 0; u < 2; u++) {
      bf16x8 a[4], b1f[2], b3f[2];
#pragma unroll
      for (int i = 0; i < 4; i++) a[i] = *(const bf16x8*)(lA + aRow[i] + cSlot[u]);
#pragma unroll
      for (int j = 0; j < 2; j++) {
        b1f[j] = *(const bf16x8*)(lB1 + bRow[j] + cSlot[u]);
        b3f[j] = *(const bf16x8*)(lB3 + bRow[j] + cSlot[u]);
      }
#pragma unroll
      for (int i = 0; i < 4; i++)
#pragma unroll
        for (int j = 0; j < 2; j++) {
          c1[i][j] = __builtin_amdgcn_mfma_f32_16x16x32_bf16(a[i], b1f[j], c1[i][j], 0, 0, 0);
          c3[i][j] = __builtin_amdgcn_mfma_f32_16x16x32_bf16(a[i], b3f[j], c3[i][j], 0, 0, 0);
        }
    }
    __syncthreads();
  }

  const int m4 = lane >> 4;
#pragma unroll
  for (int i = 0; i < 4; i++) {
#pragma unroll
    for (int j = 0; j < 2; j++) {
      int hcol = h0 + wn + j * 16 + m;
#pragma unroll
      for (int reg = 0; reg < 4; reg++) {
        int rowg = mt * 128 + wm + i * 16 + m4 * 4 + reg;
        if (rowg < Ne) {
          float v1 = c1[i][j][reg];
          float v3 = c3[i][j][reg];
          float g = gates[e * T_TOK + rowg];
          float hv = g * (v1 / (1.f + expf(-v1))) * v3;
          hbuf[(size_t)(be + rowg) * HID + hcol] = f2bf(hv);
        }
      }
    }
  }
}

// ================= GEMM2: out2[slot] = h @ W2, BK=64 (plain stores) =================
// 128m x 128d tile; per wave 64x64; 32 MFMA per barrier
__global__ __launch_bounds__(256, 3)
void gemm2_kernel(const ushort_t* __restrict__ hbuf,
                  const ushort_t* __restrict__ w2t,
                  const int* __restrict__ tok,
                  const int* __restrict__ cnt,
                  float* __restrict__ out2) {
  const int e = blockIdx.z, mt = blockIdx.y, nt = blockIdx.x;
  const int Ne = cnt[e];
  if (mt * 128 >= Ne) return;
  int be = 0;
#pragma unroll
  for (int i = 0; i < NE; i++) be += (i < e) ? cnt[i] : 0;

  __shared__ __attribute__((aligned(16))) ushort_t lA[128 * 64];
  __shared__ __attribute__((aligned(16))) ushort_t lB[128 * 64];

  const int tid = threadIdx.x, lane = tid & 63, wave = tid >> 6;
  const int kco = ((tid & 7) ^ ((tid >> 3) & 7)) * 8;

  const ushort_t* pA[4];
#pragma unroll
  for (int it = 0; it < 4; it++) {
    int rr = min(mt * 128 + it * 32 + (tid >> 3), Ne - 1);
    pA[it] = hbuf + (size_t)(be + rr) * HID + kco;
  }
  const int d0 = nt * 128;
  const ushort_t* pB[4];
#pragma unroll
  for (int it = 0; it < 4; it++) {
    int row = d0 + it * 32 + (tid >> 3);
    pB[it] = w2t + ((size_t)e * DIM + row) * HID + kco;
  }

  f32x4 c[4][4];
#pragma unroll
  for (int i = 0; i < 4; i++)
#pragma unroll
    for (int j = 0; j < 4; j++) c[i][j] = (f32x4){0.f, 0.f, 0.f, 0.f};

  const int wm = (wave >> 1) * 64, wn = (wave & 1) * 64;
  const int m = lane & 15, kq = lane >> 4;
  int aRow[4], bRow[4], cSlot[2];
#pragma unroll
  for (int i = 0; i < 4; i++) aRow[i] = (wm + i * 16 + m) * 64;
#pragma unroll
  for (int j = 0; j < 4; j++) bRow[j] = (wn + j * 16 + m) * 64;
#pragma unroll
  for (int u = 0; u < 2; u++) cSlot[u] = ((u * 4 + kq) ^ (m & 7)) * 8;

  for (int k0 = 0; k0 < HID; k0 += 64) {
#pragma unroll
    for (int it = 0; it < 4; it++) {
      gl2lds16(pA[it] + k0, lA + (it * 256 + tid) * 8);
      gl2lds16(pB[it] + k0, lB + (it * 256 + tid) * 8);
    }
    __syncthreads();
#pragma unroll
    for (int u = 0; u < 2; u++) {
      bf16x8 a[4], bf[4];
#pragma unroll
      for (int i = 0; i < 4; i++) a[i] = *(const bf16x8*)(lA + aRow[i] + cSlot[u]);
#pragma unroll
      for (int j = 0; j < 4; j++) bf[j] = *(const bf16x8*)(lB + bRow[j] + cSlot[u]);
#pragma unroll
      for (int i = 0; i < 4; i++)
#pragma unroll
        for (int j = 0; j < 4; j++)
          c[i][j] = __builtin_amdgcn_mfma_f32_16x16x32_bf16(a[i], bf[j], c[i][j], 0, 0, 0);
    }
    __syncthreads();
  }

  const int m4 = lane >> 4;
#pragma unroll
  for (int i = 0; i < 4; i++) {
    int rowg = mt * 128 + wm + i * 16 + m4 * 4;
    if (rowg >= Ne) continue;
#pragma unroll
    for (int reg = 0; reg < 4; reg++) {
      int rg = rowg + reg;
      if (rg < Ne) {
        float* orow = out2 + (size_t)(be + rg) * DIM;
#pragma unroll
        for (int j = 0; j < 4; j++) {
          int dcol = d0 + wn + j * 16 + m;
          orow[dcol] = c[i][j][reg];
        }
      }
    }
  }
}

// ================= combine: out[t] = out2[slot1(t)] + out2[slot2(t)] =================
// 512 blocks x 8 tokens
__global__ __launch_bounds__(256)
void combine_kernel(const float* __restrict__ out2, const int* __restrict__ eidx,
                    const int* __restrict__ ppos, const int* __restrict__ cnt,
                    float* __restrict__ out) {
  const int tid = threadIdx.x;
  int c[NE];
#pragma unroll
  for (int e = 0; e < NE; e++) c[e] = cnt[e];
#pragma unroll
  for (int j = 0; j < 8; j++) {
    const int t = blockIdx.x * 8 + j;
    int pk = eidx[t];
    int i1 = pk & 0xff, i2 = (pk >> 8) & 0xff;
    int pp = ppos[t];
    int p1 = pp & 0xffff, p2 = (pp >> 16) & 0xffff;
    int base1 = 0, base2 = 0;
#pragma unroll
    for (int e = 0; e < NE; e++) {
      base1 += (e < i1) ? c[e] : 0;
      base2 += (e < i2) ? c[e] : 0;
    }
    const float4* r1 = (const float4*)(out2 + (size_t)(base1 + p1) * DIM);
    const float4* r2 = (const float4*)(out2 + (size_t)(base2 + p2) * DIM);
    float4* o = (float4*)(out + (size_t)t * DIM);
    float4 a = r1[tid], b = r2[tid];
    o[tid] = make_float4(a.x + b.x, a.y + b.y, a.z + b.z, a.w + b.w);
  }
}

extern "C" void kernel_launch(void* const* d_in, const int* in_sizes, int n_in,
                              void* d_out, int out_size, void* d_ws, size_t ws_size,
                              hipStream_t stream) {
  (void)in_sizes; (void)n_in; (void)ws_size; (void)out_size;
  const float* x  = (const float*)d_in[0];
  const float* Wr = (const float*)d_in[1];
  const float* W1 = (const float*)d_in[2];
  const float* W2 = (const float*)d_in[3];
  const float* W3 = (const float*)d_in[4];
  float* out = (float*)d_out;

  char* w = (char*)d_ws;
  ushort_t* xb   = (ushort_t*)w; w += (size_t)T_TOK * DIM * 2;
  ushort_t* w1t  = (ushort_t*)w; w += (size_t)NE * DIM * HID * 2;
  ushort_t* w3t  = (ushort_t*)w; w += (size_t)NE * DIM * HID * 2;
  ushort_t* w2t  = (ushort_t*)w; w += (size_t)NE * HID * DIM * 2;
  ushort_t* hbuf = (ushort_t*)w; w += (size_t)2 * T_TOK * HID * 2;
  int*    tok   = (int*)w;    w += (size_t)NE * T_TOK * 4;
  float*  gates = (float*)w;  w += (size_t)NE * T_TOK * 4;
  int*    eidx  = (int*)w;    w += (size_t)T_TOK * 4;
  float2* gpair = (float2*)w; w += (size_t)T_TOK * 8;
  int*    cnt   = (int*)w;    w += 128;
  int*    ppos  = (int*)w;    w += (size_t)T_TOK * 4;
  // out2 aliases w1t: w1t is dead after gemm1, out2 written by gemm2 (stream-ordered)
  float*  out2  = (float*)w1t;

  prep_kernel<<<13312, 256, 0, stream>>>(x, Wr, W1, W2, W3, xb, w1t, w3t, w2t,
                                         eidx, gpair);
  compact_kernel<<<1, 1024, 0, stream>>>(eidx, gpair, cnt, tok, gates, ppos);
  gemm1_kernel<<<dim3(HID / 64, 32, NE), 256, 0, stream>>>(xb, w1t, w3t, tok, gates, cnt, hbuf);
  gemm2_kernel<<<dim3(DIM / 128, 32, NE), 256, 0, stream>>>(hbuf, w2t, tok, cnt, out2);
  combine_kernel<<<512, 256, 0, stream>>>(out2, eidx, ppos, cnt, out);
}

// Round 5
// 407.666 us; speedup vs baseline: 1.0359x; 1.0025x over previous
//
#include <hip/hip_runtime.h>
#include <hip/hip_bf16.h>
#include <stdint.h>

#define T_TOK 4096
#define DIM   1024
#define HID   2048
#define NE    8

typedef unsigned short ushort_t;
typedef __attribute__((ext_vector_type(8))) short bf16x8;
typedef __attribute__((ext_vector_type(8))) short short8_t;
typedef __attribute__((ext_vector_type(4))) float f32x4;

__device__ __forceinline__ unsigned short f2bf(float f) {
  unsigned u = __float_as_uint(f);
  unsigned r = (u + 0x7fffu + ((u >> 16) & 1u)) >> 16;
  return (unsigned short)r;
}

__device__ __forceinline__ void gl2lds16(const ushort_t* g, ushort_t* l) {
  void* gv = (void*)g;
  __builtin_amdgcn_global_load_lds((__attribute__((address_space(1))) void*)gv,
                                   (__attribute__((address_space(3))) void*)l,
                                   16, 0, 0);
}

// Blocked transposed weight layout: per expert, tiles [ht][kt][64h][64k],
// each tile 64*64 = 4096 elems = 8KB bf16, fully contiguous.
// tile base (elems) = e*R*C + (ht*(R/64) + kt)*4096   (R = k-extent of source)

// ================= fused prep =================
// blocks [0,12288): transpose+convert W1/W3/W2 -> bf16 blocked tiles
// blocks [12288,13312): router compute (no atomics) + x fp32->bf16 (4 tokens/block)
__global__ __launch_bounds__(256)
void prep_kernel(const float* __restrict__ x, const float* __restrict__ Wr,
                 const float* __restrict__ W1, const float* __restrict__ W2,
                 const float* __restrict__ W3,
                 ushort_t* __restrict__ xb,
                 ushort_t* __restrict__ w1t, ushort_t* __restrict__ w3t,
                 ushort_t* __restrict__ w2t,
                 int* __restrict__ eidx, float2* __restrict__ gpair) {
  const int b = blockIdx.x;
  const int tid = threadIdx.x;
  __shared__ float lds[64][65];

  if (b < 12288) {
    // ---- transpose+convert: src fp32 [R][C] tile -> dst bf16 blocked tile ----
    const float* src; ushort_t* dst; int R, C, cx, ry;
    const int which = b >> 12;
    const int id = b & 4095;
    const int e = id >> 9, rem = id & 511;
    if (which == 0)      { src = W1; dst = w1t; R = DIM; C = HID; cx = rem & 31; ry = rem >> 5; }
    else if (which == 1) { src = W3; dst = w3t; R = DIM; C = HID; cx = rem & 31; ry = rem >> 5; }
    else                 { src = W2; dst = w2t; R = HID; C = DIM; cx = rem & 15; ry = rem >> 4; }
    const float* s = src + (size_t)e * R * C;
    // blocked dst tile base: ht = cx, kt = ry
    ushort_t* d = dst + (size_t)e * R * C + ((size_t)cx * (R / 64) + ry) * 4096;
    const int c0 = cx * 64, r0 = ry * 64;
#pragma unroll
    for (int p = 0; p < 4; p++) {
      int idx = p * 256 + tid;
      int r = idx >> 4, c4 = idx & 15;
      float4 v = *(const float4*)(s + (size_t)(r0 + r) * C + c0 + c4 * 4);
      lds[r][c4 * 4 + 0] = v.x; lds[r][c4 * 4 + 1] = v.y;
      lds[r][c4 * 4 + 2] = v.z; lds[r][c4 * 4 + 3] = v.w;
    }
    __syncthreads();
    // 16B stores, fully contiguous 8KB per block: in-tile offset cc*64 + r8*8
#pragma unroll
    for (int p = 0; p < 2; p++) {
      int idx = p * 256 + tid;
      int cc = idx >> 3, r8 = idx & 7;
      short8_t o;
#pragma unroll
      for (int k = 0; k < 8; k++) o[k] = (short)f2bf(lds[r8 * 8 + k][cc]);
      *(short8_t*)(d + cc * 64 + r8 * 8) = o;
    }
  } else {
    // ---- router compute + x convert: one token per wave ----
    const int wave = tid >> 6;
    const int lane = tid & 63;
    const int t = (b - 12288) * 4 + wave;
    const float* xr = x + (size_t)t * DIM;
    ushort_t* xbr = xb + (size_t)t * DIM;
    float acc[NE];
#pragma unroll
    for (int e = 0; e < NE; e++) acc[e] = 0.f;
#pragma unroll
    for (int it = 0; it < 4; it++) {
      int d4 = it * 64 + lane;                 // float4 index within the row
      float4 v = ((const float4*)xr)[d4];
      ushort4 o;
      o.x = f2bf(v.x); o.y = f2bf(v.y); o.z = f2bf(v.z); o.w = f2bf(v.w);
      ((ushort4*)xbr)[d4] = o;
      const float* wr = Wr + (size_t)d4 * 4 * NE;
      float c[4] = {v.x, v.y, v.z, v.w};
#pragma unroll
      for (int cc = 0; cc < 4; cc++)
#pragma unroll
        for (int e = 0; e < NE; e++) acc[e] += c[cc] * wr[cc * NE + e];
    }
#pragma unroll
    for (int off = 32; off >= 1; off >>= 1) {
#pragma unroll
      for (int e = 0; e < NE; e++) acc[e] += __shfl_xor(acc[e], off, 64);
    }
    if (lane == 0) {
      int i1 = 0;
#pragma unroll
      for (int e = 1; e < NE; e++) if (acc[e] > acc[i1]) i1 = e;
      int i2 = (i1 == 0) ? 1 : 0;
#pragma unroll
      for (int e = 0; e < NE; e++) {
        if (e == i1) continue;
        if (acc[e] > acc[i2]) i2 = e;
      }
      float r = expf(acc[i2] - acc[i1]);       // p2/p1
      float g1 = 1.f / (1.f + r);
      eidx[t] = i1 | (i2 << 8);
      gpair[t] = make_float2(g1, 1.f - g1);
    }
  }
}

// ================= compaction: LDS atomics, one block =================
__global__ __launch_bounds__(1024)
void compact_kernel(const int* __restrict__ eidx, const float2* __restrict__ gpair,
                    int* __restrict__ cnt, int* __restrict__ tok,
                    float* __restrict__ gate, int* __restrict__ ppos) {
  __shared__ int lcnt[NE];
  const int tid = threadIdx.x;
  if (tid < NE) lcnt[tid] = 0;
  __syncthreads();
  for (int t = tid; t < T_TOK; t += 1024) {
    int pk = eidx[t];
    int i1 = pk & 0xff, i2 = (pk >> 8) & 0xff;
    float2 g = gpair[t];
    int p1 = atomicAdd(&lcnt[i1], 1);
    tok[i1 * T_TOK + p1] = t; gate[i1 * T_TOK + p1] = g.x;
    int p2 = atomicAdd(&lcnt[i2], 1);
    tok[i2 * T_TOK + p2] = t; gate[i2 * T_TOK + p2] = g.y;
    ppos[t] = p1 | (p2 << 16);
  }
  __syncthreads();
  if (tid < NE) cnt[tid] = lcnt[tid];
}

// ================= GEMM1: h = gate*silu(x@W1)*(x@W3), BK=64 =================
// 128m x 64h tile; per wave 64x32 for BOTH W1,W3; 32 MFMA per barrier
// B tiles come from blocked layout: tile (ht=nt, kt=k0/64) contiguous 8KB
__global__ __launch_bounds__(256, 3)
void gemm1_kernel(const ushort_t* __restrict__ xb,
                  const ushort_t* __restrict__ w1t,
                  const ushort_t* __restrict__ w3t,
                  const int* __restrict__ tok,
                  const float* __restrict__ gates,
                  const int* __restrict__ cnt,
                  ushort_t* __restrict__ hbuf) {
  const int e = blockIdx.z, mt = blockIdx.y, nt = blockIdx.x;
  const int Ne = cnt[e];
  if (mt * 128 >= Ne) return;
  int be = 0;
#pragma unroll
  for (int i = 0; i < NE; i++) be += (i < e) ? cnt[i] : 0;

  __shared__ __attribute__((aligned(16))) ushort_t lA[128 * 64];
  __shared__ __attribute__((aligned(16))) ushort_t lB1[64 * 64];
  __shared__ __attribute__((aligned(16))) ushort_t lB3[64 * 64];

  const int tid = threadIdx.x, lane = tid & 63, wave = tid >> 6;
  const int kco = ((tid & 7) ^ ((tid >> 3) & 7)) * 8;

  const ushort_t* pA[4];
#pragma unroll
  for (int it = 0; it < 4; it++) {
    int rowg = mt * 128 + it * 32 + (tid >> 3);
    int t = (rowg < Ne) ? tok[e * T_TOK + rowg] : 0;
    pA[it] = xb + (size_t)t * DIM + kco;
  }
  // blocked B: base of tile (ht=nt, kt=0); k-step advances by 64*64 elems = k0*64
  const size_t bbase = (size_t)e * HID * DIM + (size_t)nt * (DIM / 64) * 4096;
  const ushort_t* pB1[2];
  const ushort_t* pB3[2];
#pragma unroll
  for (int it = 0; it < 2; it++) {
    int rin = it * 32 + (tid >> 3);            // h row within tile
    pB1[it] = w1t + bbase + rin * 64 + kco;
    pB3[it] = w3t + bbase + rin * 64 + kco;
  }

  f32x4 c1[4][2], c3[4][2];
#pragma unroll
  for (int i = 0; i < 4; i++)
#pragma unroll
    for (int j = 0; j < 2; j++) {
      c1[i][j] = (f32x4){0.f, 0.f, 0.f, 0.f};
      c3[i][j] = (f32x4){0.f, 0.f, 0.f, 0.f};
    }

  const int wm = (wave >> 1) * 64, wn = (wave & 1) * 32;
  const int m = lane & 15, kq = lane >> 4;
  int aRow[4], bRow[2], cSlot[2];
#pragma unroll
  for (int i = 0; i < 4; i++) aRow[i] = (wm + i * 16 + m) * 64;
#pragma unroll
  for (int j = 0; j < 2; j++) bRow[j] = (wn + j * 16 + m) * 64;
#pragma unroll
  for (int u = 0; u < 2; u++) cSlot[u] = ((u * 4 + kq) ^ (m & 7)) * 8;

  for (int k0 = 0; k0 < DIM; k0 += 64) {
#pragma unroll
    for (int it = 0; it < 4; it++) gl2lds16(pA[it] + k0, lA + (it * 256 + tid) * 8);
    const int kofs = k0 * 64;                  // blocked: next k-tile is +4096 elems
#pragma unroll
    for (int it = 0; it < 2; it++) {
      gl2lds16(pB1[it] + kofs, lB1 + (it * 256 + tid) * 8);
      gl2lds16(pB3[it] + kofs, lB3 + (it * 256 + tid) * 8);
    }
    __syncthreads();
#pragma unroll
    for (int u = 0; u < 2; u++) {
      bf16x8 a[4], b1f[2], b3f[2];
#pragma unroll
      for (int i = 0; i < 4; i++) a[i] = *(const bf16x8*)(lA + aRow[i] + cSlot[u]);
#pragma unroll
      for (int j = 0; j < 2; j++) {
        b1f[j] = *(const bf16x8*)(lB1 + bRow[j] + cSlot[u]);
        b3f[j] = *(const bf16x8*)(lB3 + bRow[j] + cSlot[u]);
      }
#pragma unroll
      for (int i = 0; i < 4; i++)
#pragma unroll
        for (int j = 0; j < 2; j++) {
          c1[i][j] = __builtin_amdgcn_mfma_f32_16x16x32_bf16(a[i], b1f[j], c1[i][j], 0, 0, 0);
          c3[i][j] = __builtin_amdgcn_mfma_f32_16x16x32_bf16(a[i], b3f[j], c3[i][j], 0, 0, 0);
        }
    }
    __syncthreads();
  }

  const int h0 = nt * 64;
  const int m4 = lane >> 4;
#pragma unroll
  for (int i = 0; i < 4; i++) {
#pragma unroll
    for (int j = 0; j < 2; j++) {
      int hcol = h0 + wn + j * 16 + m;
#pragma unroll
      for (int reg = 0; reg < 4; reg++) {
        int rowg = mt * 128 + wm + i * 16 + m4 * 4 + reg;
        if (rowg < Ne) {
          float v1 = c1[i][j][reg];
          float v3 = c3[i][j][reg];
          float g = gates[e * T_TOK + rowg];
          float hv = g * (v1 / (1.f + expf(-v1))) * v3;
          hbuf[(size_t)(be + rowg) * HID + hcol] = f2bf(hv);
        }
      }
    }
  }
}

// ================= GEMM2: out2[slot] = h @ W2, BK=64 (plain stores) =================
// 128m x 128d tile; per wave 64x64; 32 MFMA per barrier; blocked W2 tiles
__global__ __launch_bounds__(256, 3)
void gemm2_kernel(const ushort_t* __restrict__ hbuf,
                  const ushort_t* __restrict__ w2t,
                  const int* __restrict__ tok,
                  const int* __restrict__ cnt,
                  float* __restrict__ out2) {
  const int e = blockIdx.z, mt = blockIdx.y, nt = blockIdx.x;
  const int Ne = cnt[e];
  if (mt * 128 >= Ne) return;
  int be = 0;
#pragma unroll
  for (int i = 0; i < NE; i++) be += (i < e) ? cnt[i] : 0;

  __shared__ __attribute__((aligned(16))) ushort_t lA[128 * 64];
  __shared__ __attribute__((aligned(16))) ushort_t lB[128 * 64];

  const int tid = threadIdx.x, lane = tid & 63, wave = tid >> 6;
  const int kco = ((tid & 7) ^ ((tid >> 3) & 7)) * 8;

  const ushort_t* pA[4];
#pragma unroll
  for (int it = 0; it < 4; it++) {
    int rr = min(mt * 128 + it * 32 + (tid >> 3), Ne - 1);
    pA[it] = hbuf + (size_t)(be + rr) * HID + kco;
  }
  const int d0 = nt * 128;
  const ushort_t* pB[4];
#pragma unroll
  for (int it = 0; it < 4; it++) {
    int row = d0 + it * 32 + (tid >> 3);       // n row global
    int ntile = row >> 6, rin = row & 63;
    pB[it] = w2t + (size_t)e * HID * DIM + (size_t)ntile * (HID / 64) * 4096
             + rin * 64 + kco;
  }

  f32x4 c[4][4];
#pragma unroll
  for (int i = 0; i < 4; i++)
#pragma unroll
    for (int j = 0; j < 4; j++) c[i][j] = (f32x4){0.f, 0.f, 0.f, 0.f};

  const int wm = (wave >> 1) * 64, wn = (wave & 1) * 64;
  const int m = lane & 15, kq = lane >> 4;
  int aRow[4], bRow[4], cSlot[2];
#pragma unroll
  for (int i = 0; i < 4; i++) aRow[i] = (wm + i * 16 + m) * 64;
#pragma unroll
  for (int j = 0; j < 4; j++) bRow[j] = (wn + j * 16 + m) * 64;
#pragma unroll
  for (int u = 0; u < 2; u++) cSlot[u] = ((u * 4 + kq) ^ (m & 7)) * 8;

  for (int k0 = 0; k0 < HID; k0 += 64) {
    const int kofs = k0 * 64;
#pragma unroll
    for (int it = 0; it < 4; it++) {
      gl2lds16(pA[it] + k0, lA + (it * 256 + tid) * 8);
      gl2lds16(pB[it] + kofs, lB + (it * 256 + tid) * 8);
    }
    __syncthreads();
#pragma unroll
    for (int u = 0; u < 2; u++) {
      bf16x8 a[4], bf[4];
#pragma unroll
      for (int i = 0; i < 4; i++) a[i] = *(const bf16x8*)(lA + aRow[i] + cSlot[u]);
#pragma unroll
      for (int j = 0; j < 4; j++) bf[j] = *(const bf16x8*)(lB + bRow[j] + cSlot[u]);
#pragma unroll
      for (int i = 0; i < 4; i++)
#pragma unroll
        for (int j = 0; j < 4; j++)
          c[i][j] = __builtin_amdgcn_mfma_f32_16x16x32_bf16(a[i], bf[j], c[i][j], 0, 0, 0);
    }
    __syncthreads();
  }

  const int m4 = lane >> 4;
#pragma unroll
  for (int i = 0; i < 4; i++) {
    int rowg = mt * 128 + wm + i * 16 + m4 * 4;
    if (rowg >= Ne) continue;
#pragma unroll
    for (int reg = 0; reg < 4; reg++) {
      int rg = rowg + reg;
      if (rg < Ne) {
        float* orow = out2 + (size_t)(be + rg) * DIM;
#pragma unroll
        for (int j = 0; j < 4; j++) {
          int dcol = d0 + wn + j * 16 + m;
          orow[dcol] = c[i][j][reg];
        }
      }
    }
  }
}

// ================= combine: out[t] = out2[slot1(t)] + out2[slot2(t)] =================
// 512 blocks x 8 tokens
__global__ __launch_bounds__(256)
void combine_kernel(const float* __restrict__ out2, const int* __restrict__ eidx,
                    const int* __restrict__ ppos, const int* __restrict__ cnt,
                    float* __restrict__ out) {
  const int tid = threadIdx.x;
  int c[NE];
#pragma unroll
  for (int e = 0; e < NE; e++) c[e] = cnt[e];
#pragma unroll
  for (int j = 0; j < 8; j++) {
    const int t = blockIdx.x * 8 + j;
    int pk = eidx[t];
    int i1 = pk & 0xff, i2 = (pk >> 8) & 0xff;
    int pp = ppos[t];
    int p1 = pp & 0xffff, p2 = (pp >> 16) & 0xffff;
    int base1 = 0, base2 = 0;
#pragma unroll
    for (int e = 0; e < NE; e++) {
      base1 += (e < i1) ? c[e] : 0;
      base2 += (e < i2) ? c[e] : 0;
    }
    const float4* r1 = (const float4*)(out2 + (size_t)(base1 + p1) * DIM);
    const float4* r2 = (const float4*)(out2 + (size_t)(base2 + p2) * DIM);
    float4* o = (float4*)(out + (size_t)t * DIM);
    float4 a = r1[tid], b = r2[tid];
    o[tid] = make_float4(a.x + b.x, a.y + b.y, a.z + b.z, a.w + b.w);
  }
}

extern "C" void kernel_launch(void* const* d_in, const int* in_sizes, int n_in,
                              void* d_out, int out_size, void* d_ws, size_t ws_size,
                              hipStream_t stream) {
  (void)in_sizes; (void)n_in; (void)ws_size; (void)out_size;
  const float* x  = (const float*)d_in[0];
  const float* Wr = (const float*)d_in[1];
  const float* W1 = (const float*)d_in[2];
  const float* W2 = (const float*)d_in[3];
  const float* W3 = (const float*)d_in[4];
  float* out = (float*)d_out;

  char* w = (char*)d_ws;
  ushort_t* xb   = (ushort_t*)w; w += (size_t)T_TOK * DIM * 2;
  ushort_t* w1t  = (ushort_t*)w; w += (size_t)NE * DIM * HID * 2;
  ushort_t* w3t  = (ushort_t*)w; w += (size_t)NE * DIM * HID * 2;
  ushort_t* w2t  = (ushort_t*)w; w += (size_t)NE * HID * DIM * 2;
  ushort_t* hbuf = (ushort_t*)w; w += (size_t)2 * T_TOK * HID * 2;
  int*    tok   = (int*)w;    w += (size_t)NE * T_TOK * 4;
  float*  gates = (float*)w;  w += (size_t)NE * T_TOK * 4;
  int*    eidx  = (int*)w;    w += (size_t)T_TOK * 4;
  float2* gpair = (float2*)w; w += (size_t)T_TOK * 8;
  int*    cnt   = (int*)w;    w += 128;
  int*    ppos  = (int*)w;    w += (size_t)T_TOK * 4;
  // out2 aliases w1t: w1t is dead after gemm1, out2 written by gemm2 (stream-ordered)
  float*  out2  = (float*)w1t;

  prep_kernel<<<13312, 256, 0, stream>>>(x, Wr, W1, W2, W3, xb, w1t, w3t, w2t,
                                         eidx, gpair);
  compact_kernel<<<1, 1024, 0, stream>>>(eidx, gpair, cnt, tok, gates, ppos);
  gemm1_kernel<<<dim3(HID / 64, 32, NE), 256, 0, stream>>>(xb, w1t, w3t, tok, gates, cnt, hbuf);
  gemm2_kernel<<<dim3(DIM / 128, 32, NE), 256, 0, stream>>>(hbuf, w2t, tok, cnt, out2);
  combine_kernel<<<512, 256, 0, stream>>>(out2, eidx, ppos, cnt, out);
}

// Round 6
// 406.385 us; speedup vs baseline: 1.0392x; 1.0032x over previous
//
#include <hip/hip_runtime.h>
#include <hip/hip_bf16.h>
#include <stdint.h>

#define T_TOK 4096
#define DIM   1024
#define HID   2048
#define NE    8

typedef unsigned short ushort_t;
typedef __attribute__((ext_vector_type(8))) short bf16x8;
typedef __attribute__((ext_vector_type(8))) short short8_t;
typedef __attribute__((ext_vector_type(4))) float f32x4;

__device__ __forceinline__ unsigned short f2bf(float f) {
  unsigned u = __float_as_uint(f);
  unsigned r = (u + 0x7fffu + ((u >> 16) & 1u)) >> 16;
  return (unsigned short)r;
}

__device__ __forceinline__ void gl2lds16(const ushort_t* g, ushort_t* l) {
  void* gv = (void*)g;
  __builtin_amdgcn_global_load_lds((__attribute__((address_space(1))) void*)gv,
                                   (__attribute__((address_space(3))) void*)l,
                                   16, 0, 0);
}

// Blocked transposed weight layout: per expert, tiles [ht][kt][64h][64k],
// each tile 64*64 = 4096 elems = 8KB bf16, fully contiguous.
// tile base (elems) = e*R*C + (ht*(R/64) + kt)*4096   (R = k-extent of source)

// ================= fused prep (wide reads) =================
// blocks [0,3072): transpose+convert, 64k x 256h per block (1-KB row reads)
//   [0,1024): W1   [1024,2048): W3   [2048,3072): W2
// blocks [3072,4096): router compute + x fp32->bf16 (4 tokens/block)
__global__ __launch_bounds__(256)
void prep_kernel(const float* __restrict__ x, const float* __restrict__ Wr,
                 const float* __restrict__ W1, const float* __restrict__ W2,
                 const float* __restrict__ W3,
                 ushort_t* __restrict__ xb,
                 ushort_t* __restrict__ w1t, ushort_t* __restrict__ w3t,
                 ushort_t* __restrict__ w2t,
                 int* __restrict__ eidx, float2* __restrict__ gpair) {
  const int b = blockIdx.x;
  const int tid = threadIdx.x;
  // bf16 staging, row stride 266 elems (=133 words, odd -> phase-2 column
  // reads at 8-row stride hit distinct banks)
  __shared__ ushort_t lds2[64][266];

  if (b < 3072) {
    const int which = b >> 10;
    const int id = b & 1023;
    const int e = id >> 7, rem = id & 127;
    const float* src; ushort_t* dst; int R, C, chunk, kt;
    if (which == 0)      { src = W1; dst = w1t; R = DIM; C = HID; chunk = rem >> 4; kt = rem & 15; }
    else if (which == 1) { src = W3; dst = w3t; R = DIM; C = HID; chunk = rem >> 4; kt = rem & 15; }
    else                 { src = W2; dst = w2t; R = HID; C = DIM; chunk = rem >> 5; kt = rem & 31; }
    const float* s = src + (size_t)e * R * C;
    ushort_t* dbase = dst + (size_t)e * R * C;
    const int c0 = chunk * 256, r0 = kt * 64;
    const int wv = tid >> 6, lane = tid & 63;

    // phase 1: each wave reads 16 full 1-KB rows (lane l -> float4 at col l*4)
    float4 v[16];
#pragma unroll
    for (int i = 0; i < 16; i++) {
      int r = wv * 16 + i;
      v[i] = *(const float4*)(s + (size_t)(r0 + r) * C + c0 + lane * 4);
    }
#pragma unroll
    for (int i = 0; i < 16; i++) {
      int r = wv * 16 + i;
      ushort2 o01, o23;
      o01.x = f2bf(v[i].x); o01.y = f2bf(v[i].y);
      o23.x = f2bf(v[i].z); o23.y = f2bf(v[i].w);
      *(ushort2*)&lds2[r][lane * 4]     = o01;
      *(ushort2*)&lds2[r][lane * 4 + 2] = o23;
    }
    __syncthreads();

    // phase 2: 4 contiguous 8-KB blocked tiles; unit = ushort4 (4 k's, one h)
    const int rdiv = R >> 6;
#pragma unroll
    for (int p = 0; p < 16; p++) {
      int g = p * 256 + tid;
      int ht = g >> 10, w = g & 1023, h = w >> 4, k4 = w & 15;
      int htg = chunk * 4 + ht;
      int col = ht * 64 + h;
      ushort4 o;
      o.x = lds2[k4 * 4 + 0][col];
      o.y = lds2[k4 * 4 + 1][col];
      o.z = lds2[k4 * 4 + 2][col];
      o.w = lds2[k4 * 4 + 3][col];
      *(ushort4*)(dbase + ((size_t)htg * rdiv + kt) * 4096 + h * 64 + k4 * 4) = o;
    }
  } else {
    // ---- router compute + x convert: one token per wave ----
    const int wave = tid >> 6;
    const int lane = tid & 63;
    const int t = (b - 3072) * 4 + wave;
    const float* xr = x + (size_t)t * DIM;
    ushort_t* xbr = xb + (size_t)t * DIM;
    float acc[NE];
#pragma unroll
    for (int e = 0; e < NE; e++) acc[e] = 0.f;
#pragma unroll
    for (int it = 0; it < 4; it++) {
      int d4 = it * 64 + lane;                 // float4 index within the row
      float4 v = ((const float4*)xr)[d4];
      ushort4 o;
      o.x = f2bf(v.x); o.y = f2bf(v.y); o.z = f2bf(v.z); o.w = f2bf(v.w);
      ((ushort4*)xbr)[d4] = o;
      const float* wr = Wr + (size_t)d4 * 4 * NE;
      float c[4] = {v.x, v.y, v.z, v.w};
#pragma unroll
      for (int cc = 0; cc < 4; cc++)
#pragma unroll
        for (int e = 0; e < NE; e++) acc[e] += c[cc] * wr[cc * NE + e];
    }
#pragma unroll
    for (int off = 32; off >= 1; off >>= 1) {
#pragma unroll
      for (int e = 0; e < NE; e++) acc[e] += __shfl_xor(acc[e], off, 64);
    }
    if (lane == 0) {
      int i1 = 0;
#pragma unroll
      for (int e = 1; e < NE; e++) if (acc[e] > acc[i1]) i1 = e;
      int i2 = (i1 == 0) ? 1 : 0;
#pragma unroll
      for (int e = 0; e < NE; e++) {
        if (e == i1) continue;
        if (acc[e] > acc[i2]) i2 = e;
      }
      float r = expf(acc[i2] - acc[i1]);       // p2/p1
      float g1 = 1.f / (1.f + r);
      eidx[t] = i1 | (i2 << 8);
      gpair[t] = make_float2(g1, 1.f - g1);
    }
  }
}

// ================= compaction: LDS atomics, one block =================
__global__ __launch_bounds__(1024)
void compact_kernel(const int* __restrict__ eidx, const float2* __restrict__ gpair,
                    int* __restrict__ cnt, int* __restrict__ tok,
                    float* __restrict__ gate, int* __restrict__ ppos) {
  __shared__ int lcnt[NE];
  const int tid = threadIdx.x;
  if (tid < NE) lcnt[tid] = 0;
  __syncthreads();
  for (int t = tid; t < T_TOK; t += 1024) {
    int pk = eidx[t];
    int i1 = pk & 0xff, i2 = (pk >> 8) & 0xff;
    float2 g = gpair[t];
    int p1 = atomicAdd(&lcnt[i1], 1);
    tok[i1 * T_TOK + p1] = t; gate[i1 * T_TOK + p1] = g.x;
    int p2 = atomicAdd(&lcnt[i2], 1);
    tok[i2 * T_TOK + p2] = t; gate[i2 * T_TOK + p2] = g.y;
    ppos[t] = p1 | (p2 << 16);
  }
  __syncthreads();
  if (tid < NE) cnt[tid] = lcnt[tid];
}

// ================= GEMM1: h = gate*silu(x@W1)*(x@W3), BK=64 =================
// 128m x 64h tile; per wave 64x32 for BOTH W1,W3; 32 MFMA per barrier
// B tiles come from blocked layout: tile (ht=nt, kt=k0/64) contiguous 8KB
__global__ __launch_bounds__(256, 3)
void gemm1_kernel(const ushort_t* __restrict__ xb,
                  const ushort_t* __restrict__ w1t,
                  const ushort_t* __restrict__ w3t,
                  const int* __restrict__ tok,
                  const float* __restrict__ gates,
                  const int* __restrict__ cnt,
                  ushort_t* __restrict__ hbuf) {
  const int e = blockIdx.z, mt = blockIdx.y, nt = blockIdx.x;
  const int Ne = cnt[e];
  if (mt * 128 >= Ne) return;
  int be = 0;
#pragma unroll
  for (int i = 0; i < NE; i++) be += (i < e) ? cnt[i] : 0;

  __shared__ __attribute__((aligned(16))) ushort_t lA[128 * 64];
  __shared__ __attribute__((aligned(16))) ushort_t lB1[64 * 64];
  __shared__ __attribute__((aligned(16))) ushort_t lB3[64 * 64];

  const int tid = threadIdx.x, lane = tid & 63, wave = tid >> 6;
  const int kco = ((tid & 7) ^ ((tid >> 3) & 7)) * 8;

  const ushort_t* pA[4];
#pragma unroll
  for (int it = 0; it < 4; it++) {
    int rowg = mt * 128 + it * 32 + (tid >> 3);
    int t = (rowg < Ne) ? tok[e * T_TOK + rowg] : 0;
    pA[it] = xb + (size_t)t * DIM + kco;
  }
  // blocked B: base of tile (ht=nt, kt=0); k-step advances by 64*64 elems = k0*64
  const size_t bbase = (size_t)e * HID * DIM + (size_t)nt * (DIM / 64) * 4096;
  const ushort_t* pB1[2];
  const ushort_t* pB3[2];
#pragma unroll
  for (int it = 0; it < 2; it++) {
    int rin = it * 32 + (tid >> 3);            // h row within tile
    pB1[it] = w1t + bbase + rin * 64 + kco;
    pB3[it] = w3t + bbase + rin * 64 + kco;
  }

  f32x4 c1[4][2], c3[4][2];
#pragma unroll
  for (int i = 0; i < 4; i++)
#pragma unroll
    for (int j = 0; j < 2; j++) {
      c1[i][j] = (f32x4){0.f, 0.f, 0.f, 0.f};
      c3[i][j] = (f32x4){0.f, 0.f, 0.f, 0.f};
    }

  const int wm = (wave >> 1) * 64, wn = (wave & 1) * 32;
  const int m = lane & 15, kq = lane >> 4;
  int aRow[4], bRow[2], cSlot[2];
#pragma unroll
  for (int i = 0; i < 4; i++) aRow[i] = (wm + i * 16 + m) * 64;
#pragma unroll
  for (int j = 0; j < 2; j++) bRow[j] = (wn + j * 16 + m) * 64;
#pragma unroll
  for (int u = 0; u < 2; u++) cSlot[u] = ((u * 4 + kq) ^ (m & 7)) * 8;

  for (int k0 = 0; k0 < DIM; k0 += 64) {
#pragma unroll
    for (int it = 0; it < 4; it++) gl2lds16(pA[it] + k0, lA + (it * 256 + tid) * 8);
    const int kofs = k0 * 64;                  // blocked: next k-tile is +4096 elems
#pragma unroll
    for (int it = 0; it < 2; it++) {
      gl2lds16(pB1[it] + kofs, lB1 + (it * 256 + tid) * 8);
      gl2lds16(pB3[it] + kofs, lB3 + (it * 256 + tid) * 8);
    }
    __syncthreads();
#pragma unroll
    for (int u = 0; u < 2; u++) {
      bf16x8 a[4], b1f[2], b3f[2];
#pragma unroll
      for (int i = 0; i < 4; i++) a[i] = *(const bf16x8*)(lA + aRow[i] + cSlot[u]);
#pragma unroll
      for (int j = 0; j < 2; j++) {
        b1f[j] = *(const bf16x8*)(lB1 + bRow[j] + cSlot[u]);
        b3f[j] = *(const bf16x8*)(lB3 + bRow[j] + cSlot[u]);
      }
#pragma unroll
      for (int i = 0; i < 4; i++)
#pragma unroll
        for (int j = 0; j < 2; j++) {
          c1[i][j] = __builtin_amdgcn_mfma_f32_16x16x32_bf16(a[i], b1f[j], c1[i][j], 0, 0, 0);
          c3[i][j] = __builtin_amdgcn_mfma_f32_16x16x32_bf16(a[i], b3f[j], c3[i][j], 0, 0, 0);
        }
    }
    __syncthreads();
  }

  const int h0 = nt * 64;
  const int m4 = lane >> 4;
#pragma unroll
  for (int i = 0; i < 4; i++) {
#pragma unroll
    for (int j = 0; j < 2; j++) {
      int hcol = h0 + wn + j * 16 + m;
#pragma unroll
      for (int reg = 0; reg < 4; reg++) {
        int rowg = mt * 128 + wm + i * 16 + m4 * 4 + reg;
        if (rowg < Ne) {
          float v1 = c1[i][j][reg];
          float v3 = c3[i][j][reg];
          float g = gates[e * T_TOK + rowg];
          float hv = g * (v1 / (1.f + expf(-v1))) * v3;
          hbuf[(size_t)(be + rowg) * HID + hcol] = f2bf(hv);
        }
      }
    }
  }
}

// ================= GEMM2: out2[slot] = h @ W2, BK=64 (plain stores) =================
// 128m x 128d tile; per wave 64x64; 32 MFMA per barrier; blocked W2 tiles
__global__ __launch_bounds__(256, 3)
void gemm2_kernel(const ushort_t* __restrict__ hbuf,
                  const ushort_t* __restrict__ w2t,
                  const int* __restrict__ tok,
                  const int* __restrict__ cnt,
                  float* __restrict__ out2) {
  const int e = blockIdx.z, mt = blockIdx.y, nt = blockIdx.x;
  const int Ne = cnt[e];
  if (mt * 128 >= Ne) return;
  int be = 0;
#pragma unroll
  for (int i = 0; i < NE; i++) be += (i < e) ? cnt[i] : 0;

  __shared__ __attribute__((aligned(16))) ushort_t lA[128 * 64];
  __shared__ __attribute__((aligned(16))) ushort_t lB[128 * 64];

  const int tid = threadIdx.x, lane = tid & 63, wave = tid >> 6;
  const int kco = ((tid & 7) ^ ((tid >> 3) & 7)) * 8;

  const ushort_t* pA[4];
#pragma unroll
  for (int it = 0; it < 4; it++) {
    int rr = min(mt * 128 + it * 32 + (tid >> 3), Ne - 1);
    pA[it] = hbuf + (size_t)(be + rr) * HID + kco;
  }
  const int d0 = nt * 128;
  const ushort_t* pB[4];
#pragma unroll
  for (int it = 0; it < 4; it++) {
    int row = d0 + it * 32 + (tid >> 3);       // n row global
    int ntile = row >> 6, rin = row & 63;
    pB[it] = w2t + (size_t)e * HID * DIM + (size_t)ntile * (HID / 64) * 4096
             + rin * 64 + kco;
  }

  f32x4 c[4][4];
#pragma unroll
  for (int i = 0; i < 4; i++)
#pragma unroll
    for (int j = 0; j < 4; j++) c[i][j] = (f32x4){0.f, 0.f, 0.f, 0.f};

  const int wm = (wave >> 1) * 64, wn = (wave & 1) * 64;
  const int m = lane & 15, kq = lane >> 4;
  int aRow[4], bRow[4], cSlot[2];
#pragma unroll
  for (int i = 0; i < 4; i++) aRow[i] = (wm + i * 16 + m) * 64;
#pragma unroll
  for (int j = 0; j < 4; j++) bRow[j] = (wn + j * 16 + m) * 64;
#pragma unroll
  for (int u = 0; u < 2; u++) cSlot[u] = ((u * 4 + kq) ^ (m & 7)) * 8;

  for (int k0 = 0; k0 < HID; k0 += 64) {
    const int kofs = k0 * 64;
#pragma unroll
    for (int it = 0; it < 4; it++) {
      gl2lds16(pA[it] + k0, lA + (it * 256 + tid) * 8);
      gl2lds16(pB[it] + kofs, lB + (it * 256 + tid) * 8);
    }
    __syncthreads();
#pragma unroll
    for (int u = 0; u < 2; u++) {
      bf16x8 a[4], bf[4];
#pragma unroll
      for (int i = 0; i < 4; i++) a[i] = *(const bf16x8*)(lA + aRow[i] + cSlot[u]);
#pragma unroll
      for (int j = 0; j < 4; j++) bf[j] = *(const bf16x8*)(lB + bRow[j] + cSlot[u]);
#pragma unroll
      for (int i = 0; i < 4; i++)
#pragma unroll
        for (int j = 0; j < 4; j++)
          c[i][j] = __builtin_amdgcn_mfma_f32_16x16x32_bf16(a[i], bf[j], c[i][j], 0, 0, 0);
    }
    __syncthreads();
  }

  const int m4 = lane >> 4;
#pragma unroll
  for (int i = 0; i < 4; i++) {
    int rowg = mt * 128 + wm + i * 16 + m4 * 4;
    if (rowg >= Ne) continue;
#pragma unroll
    for (int reg = 0; reg < 4; reg++) {
      int rg = rowg + reg;
      if (rg < Ne) {
        float* orow = out2 + (size_t)(be + rg) * DIM;
#pragma unroll
        for (int j = 0; j < 4; j++) {
          int dcol = d0 + wn + j * 16 + m;
          orow[dcol] = c[i][j][reg];
        }
      }
    }
  }
}

// ================= combine: out[t] = out2[slot1(t)] + out2[slot2(t)] =================
// 512 blocks x 8 tokens
__global__ __launch_bounds__(256)
void combine_kernel(const float* __restrict__ out2, const int* __restrict__ eidx,
                    const int* __restrict__ ppos, const int* __restrict__ cnt,
                    float* __restrict__ out) {
  const int tid = threadIdx.x;
  int c[NE];
#pragma unroll
  for (int e = 0; e < NE; e++) c[e] = cnt[e];
#pragma unroll
  for (int j = 0; j < 8; j++) {
    const int t = blockIdx.x * 8 + j;
    int pk = eidx[t];
    int i1 = pk & 0xff, i2 = (pk >> 8) & 0xff;
    int pp = ppos[t];
    int p1 = pp & 0xffff, p2 = (pp >> 16) & 0xffff;
    int base1 = 0, base2 = 0;
#pragma unroll
    for (int e = 0; e < NE; e++) {
      base1 += (e < i1) ? c[e] : 0;
      base2 += (e < i2) ? c[e] : 0;
    }
    const float4* r1 = (const float4*)(out2 + (size_t)(base1 + p1) * DIM);
    const float4* r2 = (const float4*)(out2 + (size_t)(base2 + p2) * DIM);
    float4* o = (float4*)(out + (size_t)t * DIM);
    float4 a = r1[tid], b = r2[tid];
    o[tid] = make_float4(a.x + b.x, a.y + b.y, a.z + b.z, a.w + b.w);
  }
}

extern "C" void kernel_launch(void* const* d_in, const int* in_sizes, int n_in,
                              void* d_out, int out_size, void* d_ws, size_t ws_size,
                              hipStream_t stream) {
  (void)in_sizes; (void)n_in; (void)ws_size; (void)out_size;
  const float* x  = (const float*)d_in[0];
  const float* Wr = (const float*)d_in[1];
  const float* W1 = (const float*)d_in[2];
  const float* W2 = (const float*)d_in[3];
  const float* W3 = (const float*)d_in[4];
  float* out = (float*)d_out;

  char* w = (char*)d_ws;
  ushort_t* xb   = (ushort_t*)w; w += (size_t)T_TOK * DIM * 2;
  ushort_t* w1t  = (ushort_t*)w; w += (size_t)NE * DIM * HID * 2;
  ushort_t* w3t  = (ushort_t*)w; w += (size_t)NE * DIM * HID * 2;
  ushort_t* w2t  = (ushort_t*)w; w += (size_t)NE * HID * DIM * 2;
  ushort_t* hbuf = (ushort_t*)w; w += (size_t)2 * T_TOK * HID * 2;
  int*    tok   = (int*)w;    w += (size_t)NE * T_TOK * 4;
  float*  gates = (float*)w;  w += (size_t)NE * T_TOK * 4;
  int*    eidx  = (int*)w;    w += (size_t)T_TOK * 4;
  float2* gpair = (float2*)w; w += (size_t)T_TOK * 8;
  int*    cnt   = (int*)w;    w += 128;
  int*    ppos  = (int*)w;    w += (size_t)T_TOK * 4;
  // out2 aliases w1t: w1t is dead after gemm1, out2 written by gemm2 (stream-ordered)
  float*  out2  = (float*)w1t;

  prep_kernel<<<4096, 256, 0, stream>>>(x, Wr, W1, W2, W3, xb, w1t, w3t, w2t,
                                        eidx, gpair);
  compact_kernel<<<1, 1024, 0, stream>>>(eidx, gpair, cnt, tok, gates, ppos);
  gemm1_kernel<<<dim3(HID / 64, 32, NE), 256, 0, stream>>>(xb, w1t, w3t, tok, gates, cnt, hbuf);
  gemm2_kernel<<<dim3(DIM / 128, 32, NE), 256, 0, stream>>>(hbuf, w2t, tok, cnt, out2);
  combine_kernel<<<512, 256, 0, stream>>>(out2, eidx, ppos, cnt, out);
}